// Round 14
// baseline (264.754 us; speedup 1.0000x reference)
//
#include <hip/hip_runtime.h>
#include <stdint.h>

#define BS   8
#define CH   256    // C
#define LSEQ 4096   // H*W
#define DIN  256    // INNER
#define NT2  128    // number of KV tiles (32 rows each)
#define KT2  32     // kv rows per tile

typedef __bf16 bf16x8 __attribute__((ext_vector_type(8)));
typedef __bf16 bf16x4 __attribute__((ext_vector_type(4)));
typedef float  f32x4  __attribute__((ext_vector_type(4)));

// async global->LDS, 16B per lane; LDS dest = wave-uniform base + lane*16
__device__ __forceinline__ void gload_lds16(const void* g, void* l) {
    __builtin_amdgcn_global_load_lds(
        (const __attribute__((address_space(1))) uint32_t*)g,
        (__attribute__((address_space(3))) uint32_t*)l, 16, 0, 0);
}

#define CEXP_FOLD (1.4426950408889634f / 16.0f)   // log2(e)/round(sqrt(256),2)

// ---------------------------------------------------------------------------
// Kernel 1: QKV projection (identical to R13).
// which==0 -> Q linear [l][i] bf16, PRE-SCALED by CEXP_FOLD.
// which==1 -> K swizzled image: byte = row*512 + ((2i)^((row&7)<<4)).
// which==2 -> V image at +16384: byte = (d>>1)*128 +
//             (((d&1)*64 + 2*(l&31)) ^ (((d>>1)&7)<<4)).
// Tile stride 32KB; base = (b*128 + t2) << 15.
// ---------------------------------------------------------------------------
__global__ __launch_bounds__(256) void qkv_proj_kernel(
    const float* __restrict__ x,
    const float* __restrict__ Wq, const float* __restrict__ bq,
    const float* __restrict__ Wk, const float* __restrict__ bk,
    const float* __restrict__ Wv, const float* __restrict__ bv,
    __bf16* __restrict__ Q, uint8_t* __restrict__ KV)
{
    const int b     = blockIdx.z;
    const int which = blockIdx.y;
    const int l0    = blockIdx.x * 64;

    const float* W    = (which == 0) ? Wq : (which == 1) ? Wk : Wv;
    const float* bias = (which == 0) ? bq : (which == 1) ? bk : bv;
    const float* X    = x + (size_t)b * CH * LSEQ;

    __shared__ __align__(16) __bf16 sXt[64][40];   // [l][c]
    __shared__ __align__(16) __bf16 sW[256][40];   // [i][c]

    const int tid  = threadIdx.x;
    const int wv   = tid >> 6;
    const int lane = tid & 63;
    const int g    = lane >> 4;
    const int n16  = lane & 15;

    f32x4 acc[4][4];
    #pragma unroll
    for (int i = 0; i < 4; ++i)
        #pragma unroll
        for (int j = 0; j < 4; ++j)
            acc[i][j] = f32x4{0.f, 0.f, 0.f, 0.f};

    for (int kk = 0; kk < 8; ++kk) {
        const int c0 = kk * 32;
        __syncthreads();
        #pragma unroll
        for (int p = 0; p < 8; ++p) {
            const int i  = p * 32 + (tid >> 3);
            const int c4 = (tid & 7) * 4;
            const float4 v = *(const float4*)(W + (size_t)i * CH + c0 + c4);
            bf16x4 pk = { (__bf16)v.x, (__bf16)v.y, (__bf16)v.z, (__bf16)v.w };
            *(bf16x4*)&sW[i][c4] = pk;
        }
        #pragma unroll
        for (int p = 0; p < 2; ++p) {
            const int c  = p * 16 + (tid >> 4);
            const int l4 = (tid & 15) * 4;
            const float4 v = *(const float4*)(X + (size_t)(c0 + c) * LSEQ + l0 + l4);
            sXt[l4 + 0][c] = (__bf16)v.x;
            sXt[l4 + 1][c] = (__bf16)v.y;
            sXt[l4 + 2][c] = (__bf16)v.z;
            sXt[l4 + 3][c] = (__bf16)v.w;
        }
        __syncthreads();

        bf16x8 af[4], bfr[4];
        #pragma unroll
        for (int mr = 0; mr < 4; ++mr)
            af[mr] = *(const bf16x8*)&sXt[mr * 16 + n16][g * 8];
        #pragma unroll
        for (int nc = 0; nc < 4; ++nc)
            bfr[nc] = *(const bf16x8*)&sW[wv * 64 + nc * 16 + n16][g * 8];
        #pragma unroll
        for (int mr = 0; mr < 4; ++mr)
            #pragma unroll
            for (int nc = 0; nc < 4; ++nc)
                acc[mr][nc] = __builtin_amdgcn_mfma_f32_16x16x32_bf16(
                    af[mr], bfr[nc], acc[mr][nc], 0, 0, 0);
    }

    // D fragment: row l = mr*16 + g*4 + r, col i = nc*16 + n16 (+wv*64)
    if (which == 0) {
        __bf16* out = Q + (size_t)b * LSEQ * DIN;
        #pragma unroll
        for (int nc = 0; nc < 4; ++nc) {
            const int icol = wv * 64 + nc * 16 + n16;
            const float bb = bias[icol];
            #pragma unroll
            for (int mr = 0; mr < 4; ++mr) {
                const int lrow = l0 + mr * 16 + g * 4;
                #pragma unroll
                for (int r = 0; r < 4; ++r)
                    out[(size_t)(lrow + r) * DIN + icol] =
                        (__bf16)((acc[mr][nc][r] + bb) * CEXP_FOLD);
            }
        }
    } else if (which == 1) {
        #pragma unroll
        for (int nc = 0; nc < 4; ++nc) {
            const int icol = wv * 64 + nc * 16 + n16;
            const float bb = bias[icol];
            #pragma unroll
            for (int mr = 0; mr < 4; ++mr) {
                #pragma unroll
                for (int r = 0; r < 4; ++r) {
                    const int lrow = l0 + mr * 16 + g * 4 + r;
                    const int t2 = lrow >> 5, row = lrow & 31;
                    const size_t off = ((size_t)(b * NT2 + t2) << 15)
                                     + (size_t)row * 512
                                     + ((icol * 2) ^ ((row & 7) << 4));
                    *(__bf16*)(KV + off) = (__bf16)(acc[mr][nc][r] + bb);
                }
            }
        }
    } else {
        #pragma unroll
        for (int nc = 0; nc < 4; ++nc) {
            const int d  = wv * 64 + nc * 16 + n16;
            const float bb = bias[d];
            #pragma unroll
            for (int mr = 0; mr < 4; ++mr) {
                const int lrow = l0 + mr * 16 + g * 4;   // 4 consecutive l (8B run)
                const int t2 = lrow >> 5, c = lrow & 31;
                bf16x4 pk;
                #pragma unroll
                for (int r = 0; r < 4; ++r)
                    pk[r] = (__bf16)(acc[mr][nc][r] + bb);
                const size_t off = ((size_t)(b * NT2 + t2) << 15) + 16384
                                 + (size_t)(d >> 1) * 128
                                 + ((((d & 1) * 64) + 2 * c) ^ (((d >> 1) & 7) << 4));
                *(bf16x4*)(KV + off) = pk;
            }
        }
    }
}

// ---------------------------------------------------------------------------
// Kernel 2: flash attention v11 — R10 QK/softmax + (64q x 64d) PV partition.
// PV re-read reduction: all 4 waves previously read ALL V (64KB/tile/block);
// now wave wv owns d-quarter [wv*64, wv*64+64) for ALL 64 q-rows: V-reads
// 16->4KB/wave, P-reads 1->4KB/wave; block LDS traffic 168->132KB/tile (-21%).
// Same 16 MFMAs/wave/tile (4 qg x 4 dg, K=32), same fragment read patterns
// as R10 (conflicts unchanged — R11's loss was the 32x32 access shape).
// P is now cross-wave: extra lgkmcnt(0)+s_barrier per tile (vmcnt prefetch
// stays in flight); scl via shS + per-wave flags (read only on rare rescale);
// l via in-register sum (ones-MFMA dropped: -4 VGPR -4 AGPR pays for af[4]).
// Cliff rule: combined VGPR+AGPR <= ~196; falsifier = occupancy ~11%.
// ---------------------------------------------------------------------------
__global__ __launch_bounds__(256) void attn_kernel(
    const __bf16* __restrict__ Q, const uint8_t* __restrict__ KV,
    __bf16* __restrict__ O)
{
    const int b   = blockIdx.x;
    const int q0  = blockIdx.y * 64;
    const int tid = threadIdx.x;
    const int wv  = tid >> 6, lane = tid & 63, g = lane >> 4, n16 = lane & 15;

    __shared__ __align__(1024) uint8_t sKV[2][32768];  // dbuf 32-row KV tiles
    __shared__ __align__(1024) uint8_t sP[4096];       // P [64 q][32 kj], pair-swizzled
    __shared__ float    shS[64];                       // per-tile rescale factors
    __shared__ float    shL[64];                       // final denominators
    __shared__ uint32_t shFlg[4];                      // per-wave rescale flags

    // Q fragments (pre-scaled): row q0 + wv*16 + n16; used as mfma B-operand
    bf16x8 qf[8];
    {
        const __bf16* Qrow = Q + ((size_t)b * LSEQ + q0 + wv * 16 + n16) * DIN;
        #pragma unroll
        for (int ks = 0; ks < 8; ++ks)
            qf[ks] = *(const bf16x8*)(Qrow + ks * 32 + g * 8);
    }

    float m_i = -__builtin_inff();   // running max for q = q0+wv*16+n16 (log2 units)
    float l_i = 0.f;                 // running denom for that q (g-uniform)
    f32x4 accO[4][4];                // [qg][dg]: rows qg*16+g*4+r, cols wv*64+dg*16+n16
    #pragma unroll
    for (int qg = 0; qg < 4; ++qg)
        #pragma unroll
        for (int dg = 0; dg < 4; ++dg)
            accO[qg][dg] = f32x4{0.f, 0.f, 0.f, 0.f};

    const uint8_t* KVb = KV + ((size_t)b * NT2 << 15);
    const float DEFER_TH = 8.0f;   // log2 units: P bounded by 2^8

    // prologue: stage tile 0 (256 thr x 16B x 8 = 32KB)
    #pragma unroll
    for (int p = 0; p < 8; ++p) {
        const int off = p * 4096 + tid * 16;
        gload_lds16(KVb + off, &sKV[0][off]);
    }

    // P-store addressing (row = q = wv*16 + n16, fixed per lane):
    const int prow  = wv * 16 + n16;
    const int pbase = (prow >> 1) * 128;
    const int pswz  = ((prow >> 1) & 7) << 4;
    const int phalf = (prow & 1) * 64;

    for (int t = 0; t < NT2; ++t) {
        const int buf = t & 1;
        if (t + 1 < NT2) {
            const uint8_t* src = KVb + ((size_t)(t + 1) << 15);
            #pragma unroll
            for (int p = 0; p < 8; ++p) {
                const int off = p * 4096 + tid * 16;
                gload_lds16(src + off, &sKV[buf ^ 1][off]);
            }
            asm volatile("s_waitcnt vmcnt(8)" ::: "memory");  // cur tile done, next in flight
        } else {
            asm volatile("s_waitcnt vmcnt(0)" ::: "memory");
        }
        __builtin_amdgcn_s_barrier();                          // B1: tile staged
        asm volatile("" ::: "memory");

        const uint8_t* kb = sKV[buf];

        // ---- S^T = K*Q^T : D[kj][q]; lane holds kj = {g*4+r, 16+g*4+r}, q = n16 ----
        f32x4 st0 = f32x4{0.f, 0.f, 0.f, 0.f};
        f32x4 st1 = f32x4{0.f, 0.f, 0.f, 0.f};
        __builtin_amdgcn_s_setprio(1);
        #pragma unroll
        for (int ks = 0; ks < 8; ++ks) {
            const int r0 = n16;          // kj rows 0-15
            const int r1 = 16 + n16;     // kj rows 16-31
            const bf16x8 kf0 = *(const bf16x8*)(kb + r0 * 512
                                + ((ks * 64 + g * 16) ^ ((r0 & 7) << 4)));
            const bf16x8 kf1 = *(const bf16x8*)(kb + r1 * 512
                                + ((ks * 64 + g * 16) ^ ((r1 & 7) << 4)));
            st0 = __builtin_amdgcn_mfma_f32_16x16x32_bf16(kf0, qf[ks], st0, 0, 0, 0);
            st1 = __builtin_amdgcn_mfma_f32_16x16x32_bf16(kf1, qf[ks], st1, 0, 0, 0);
        }
        __builtin_amdgcn_s_setprio(0);

        // ---- softmax for q = n16 (g-uniform after reduce) ----
        float mx = fmaxf(fmaxf(fmaxf(st0[0], st0[1]), fmaxf(st0[2], st0[3])),
                         fmaxf(fmaxf(st1[0], st1[1]), fmaxf(st1[2], st1[3])));
        mx = fmaxf(mx, __shfl_xor(mx, 16));
        mx = fmaxf(mx, __shfl_xor(mx, 32));
        float scl = 1.f;
        uint32_t resc = 0;
        if (!__all(mx - m_i <= DEFER_TH)) {
            const float mnew = fmaxf(m_i, mx);
            scl = exp2f(m_i - mnew);
            m_i = mnew;
            l_i *= scl;
            resc = 1;
        }

        // ---- P = exp2(S'-m); packed bf16x4 stores; in-register l sum ----
        {
            float pv0[4], pv1[4];
            bf16x4 pk0, pk1;
            #pragma unroll
            for (int r = 0; r < 4; ++r) {
                pv0[r] = exp2f(st0[r] - m_i);
                pv1[r] = exp2f(st1[r] - m_i);
                pk0[r] = (__bf16)pv0[r];
                pk1[r] = (__bf16)pv1[r];
            }
            float s = ((pv0[0] + pv0[1]) + (pv0[2] + pv0[3]))
                    + ((pv1[0] + pv1[1]) + (pv1[2] + pv1[3]));
            s += __shfl_xor(s, 16);
            s += __shfl_xor(s, 32);
            l_i += s;
            const int c0b = 2 * (g * 4);          // kj cols g*4..g*4+3 (8B run)
            *(bf16x4*)(sP + pbase + ((phalf + c0b) ^ pswz))      = pk0;
            *(bf16x4*)(sP + pbase + ((phalf + c0b + 32) ^ pswz)) = pk1;  // +16 kj
        }
        if (lane < 16) shS[wv * 16 + lane] = scl;
        if (lane == 0) shFlg[wv] = resc;
        asm volatile("s_waitcnt lgkmcnt(0)" ::: "memory");     // P + scl written
        __builtin_amdgcn_s_barrier();                          // B2: P visible
        asm volatile("" ::: "memory");

        // ---- cross-wave rescale of accO (rare; block-uniform via flags) ----
        const uint32_t any = shFlg[0] | shFlg[1] | shFlg[2] | shFlg[3];
        if (any) {
            #pragma unroll
            for (int qg = 0; qg < 4; ++qg) {
                float sr[4];
                #pragma unroll
                for (int r = 0; r < 4; ++r)
                    sr[r] = shS[qg * 16 + g * 4 + r];
                #pragma unroll
                for (int dg = 0; dg < 4; ++dg)
                    #pragma unroll
                    for (int r = 0; r < 4; ++r)
                        accO[qg][dg][r] *= sr[r];
            }
        }

        // ---- PV (64q x 64d): af[qg] = P rows qg*16+n16; vf = V d-quarter ----
        bf16x8 af[4];
        #pragma unroll
        for (int qg = 0; qg < 4; ++qg) {
            const int arow = qg * 16 + n16;
            af[qg] = *(const bf16x8*)(sP + (arow >> 1) * 128
                       + ((((arow & 1) * 64) + g * 16) ^ (((arow >> 1) & 7) << 4)));
        }
        __builtin_amdgcn_s_setprio(1);
        #pragma unroll
        for (int dg = 0; dg < 4; ++dg) {
            const int d = wv * 64 + dg * 16 + n16;
            const bf16x8 vf = *(const bf16x8*)(kb + 16384 + (d >> 1) * 128
                               + ((((d & 1) * 64) + g * 16) ^ (((d >> 1) & 7) << 4)));
            #pragma unroll
            for (int qg = 0; qg < 4; ++qg)
                accO[qg][dg] = __builtin_amdgcn_mfma_f32_16x16x32_bf16(
                    af[qg], vf, accO[qg][dg], 0, 0, 0);
        }
        __builtin_amdgcn_s_setprio(0);

        asm volatile("" ::: "memory");
        __builtin_amdgcn_s_barrier();   // B3: buf + sP free for overwrite
    }

    // ---- epilogue: exchange l; O rows q0+qg*16+g*4+r, cols wv*64+dg*16+n16 ----
    if (lane < 16) shL[wv * 16 + lane] = l_i;
    __syncthreads();
    __bf16* Ob = O + ((size_t)b * LSEQ + q0) * DIN;
    #pragma unroll
    for (int qg = 0; qg < 4; ++qg) {
        float inv[4];
        #pragma unroll
        for (int r = 0; r < 4; ++r)
            inv[r] = 1.f / shL[qg * 16 + g * 4 + r];
        #pragma unroll
        for (int dg = 0; dg < 4; ++dg) {
            const int dcol = wv * 64 + dg * 16 + n16;
            #pragma unroll
            for (int r = 0; r < 4; ++r)
                Ob[(size_t)(qg * 16 + g * 4 + r) * DIN + dcol] =
                    (__bf16)(accO[qg][dg][r] * inv[r]);
        }
    }
}

// ---------------------------------------------------------------------------
// Kernel 3: output projection (identical to R13).
// ---------------------------------------------------------------------------
__global__ __launch_bounds__(256) void out_proj_kernel(
    const float* __restrict__ Wo, const float* __restrict__ bo,
    const __bf16* __restrict__ O, float* __restrict__ out)
{
    const int b   = blockIdx.z;
    const int c0  = blockIdx.y * 64;
    const int l0  = blockIdx.x * 256;
    const int tid = threadIdx.x;
    const int wv  = tid >> 6, lane = tid & 63, g = lane >> 4, n16 = lane & 15;

    __shared__ __align__(16) __bf16 sWo[64][40];   // [c][i]
    __shared__ __align__(16) __bf16 sO[256][40];   // [l][i]

    const __bf16* Ob = O + (size_t)b * LSEQ * DIN;

    f32x4 acc[4][4];
    #pragma unroll
    for (int i = 0; i < 4; ++i)
        #pragma unroll
        for (int j = 0; j < 4; ++j)
            acc[i][j] = f32x4{0.f, 0.f, 0.f, 0.f};

    for (int kk = 0; kk < 8; ++kk) {
        const int i0 = kk * 32;
        __syncthreads();
        #pragma unroll
        for (int p = 0; p < 2; ++p) {
            const int c  = p * 32 + (tid >> 3);
            const int i4 = (tid & 7) * 4;
            const float4 v = *(const float4*)(Wo + (size_t)(c0 + c) * DIN + i0 + i4);
            bf16x4 pk = { (__bf16)v.x, (__bf16)v.y, (__bf16)v.z, (__bf16)v.w };
            *(bf16x4*)&sWo[c][i4] = pk;
        }
        #pragma unroll
        for (int p = 0; p < 4; ++p) {
            const int l  = p * 64 + (tid >> 2);
            const int sg = tid & 3;
            *(uint4*)&sO[l][sg * 8] = *(const uint4*)(Ob + (size_t)(l0 + l) * DIN + i0 + sg * 8);
        }
        __syncthreads();

        bf16x8 af[4], bfr[4];
        #pragma unroll
        for (int mr = 0; mr < 4; ++mr)
            af[mr] = *(const bf16x8*)&sWo[mr * 16 + n16][g * 8];
        #pragma unroll
        for (int nc = 0; nc < 4; ++nc)
            bfr[nc] = *(const bf16x8*)&sO[wv * 64 + nc * 16 + n16][g * 8];
        #pragma unroll
        for (int mr = 0; mr < 4; ++mr)
            #pragma unroll
            for (int nc = 0; nc < 4; ++nc)
                acc[mr][nc] = __builtin_amdgcn_mfma_f32_16x16x32_bf16(
                    af[mr], bfr[nc], acc[mr][nc], 0, 0, 0);
    }

    #pragma unroll
    for (int mr = 0; mr < 4; ++mr) {
        const int c = c0 + mr * 16 + g * 4;
        #pragma unroll
        for (int nc = 0; nc < 4; ++nc) {
            const int l = l0 + wv * 64 + nc * 16 + n16;
            #pragma unroll
            for (int r = 0; r < 4; ++r)
                out[((size_t)b * CH + c + r) * LSEQ + l] = acc[mr][nc][r] + bo[c + r];
        }
    }
}

// ---------------------------------------------------------------------------
extern "C" void kernel_launch(void* const* d_in, const int* in_sizes, int n_in,
                              void* d_out, int out_size, void* d_ws, size_t ws_size,
                              hipStream_t stream)
{
    const float* x  = (const float*)d_in[0];
    const float* Wq = (const float*)d_in[1];
    const float* bq = (const float*)d_in[2];
    const float* Wk = (const float*)d_in[3];
    const float* bk = (const float*)d_in[4];
    const float* Wv = (const float*)d_in[5];
    const float* bv = (const float*)d_in[6];
    const float* Wo = (const float*)d_in[7];
    const float* bo = (const float*)d_in[8];
    float* out = (float*)d_out;

    // ws: Q bf16 16MB | KV swizzled tile images 32MB | O bf16 16MB = 64MB
    __bf16*  Q  = (__bf16*)d_ws;
    uint8_t* KV = (uint8_t*)d_ws + (16u << 20);
    __bf16*  O  = (__bf16*)((uint8_t*)d_ws + (48u << 20));

    qkv_proj_kernel<<<dim3(LSEQ / 64, 3, BS), 256, 0, stream>>>(
        x, Wq, bq, Wk, bk, Wv, bv, Q, KV);
    attn_kernel<<<dim3(BS, LSEQ / 64), 256, 0, stream>>>(Q, KV, O);
    out_proj_kernel<<<dim3(LSEQ / 256, CH / 64, BS), 256, 0, stream>>>(Wo, bo, O, out);
}